// Round 1
// baseline (188.639 us; speedup 1.0000x reference)
//
#include <hip/hip_runtime.h>
#include <math.h>

// Shapes: B=128, S=192, N=32, PREC_DIM=2, E=64, H=4, D=16, FF=256, M=24576.
namespace {

constexpr int S_   = 192;
constexpr int TPW  = 8;     // tokens per wave (phase-B tile)
constexpr int WVB  = 4;     // waves per block
// tokens per block = 32; grid = 24576/32 = 768 blocks = 3 per CU.

__launch_bounds__(256, 3)
__global__ void prec_fused(
    const float* __restrict__ prec,  const int*   __restrict__ tmask,
    const float* __restrict__ We,    const float* __restrict__ be,
    const float* __restrict__ Wq,    const float* __restrict__ Wk,
    const float* __restrict__ Wv,    const float* __restrict__ Wo,
    const float* __restrict__ bo,    const float* __restrict__ g1,
    const float* __restrict__ bb1,   const float* __restrict__ W1,
    const float* __restrict__ b1,    const float* __restrict__ W2,
    const float* __restrict__ b2,    const float* __restrict__ g2,
    const float* __restrict__ bb2,   float* __restrict__ out)
{
  __shared__ float sWe0[64], sWe1[64], sbe[64];
  __shared__ float sWq[256], sWk[256], sWv[256];
  __shared__ float sbo[64], sg1[64], sbb1[64], sb1[256], sb2c[64], sg2[64], sbb2[64];
  // per-wave scratch: phase A transpose tile [32][64] (xor-swizzled) / phase B h1 [8][256]
  __shared__ __align__(16) float scratch[WVB][2048];
  // per-wave: oh[8][64] in phase A, then x[8][64] in phase B (overlaid)
  __shared__ __align__(16) float sxoh[WVB][TPW][64];

  const int tid = threadIdx.x;
  // ---- stage small shared weights ----
  if (tid < 64) {
    sWe0[tid] = We[tid];      sWe1[tid] = We[64 + tid]; sbe[tid]  = be[tid];
    sbo[tid]  = bo[tid];      sg1[tid]  = g1[tid];      sbb1[tid] = bb1[tid];
    sb2c[tid] = b2[tid];      sg2[tid]  = g2[tid];      sbb2[tid] = bb2[tid];
  }
  { // 256 threads
    sWq[tid] = Wq[tid]; sWk[tid] = Wk[tid]; sWv[tid] = Wv[tid]; sb1[tid] = b1[tid];
  }
  __syncthreads();

  const int wv   = tid >> 6;
  const int lane = tid & 63;
  const int u    = lane >> 5;   // feature half
  const int n    = lane & 31;   // precedence slot (row)
  const int tokbase = (blockIdx.x * WVB + wv) * TPW;
  float* trans = scratch[wv];

  // ================= Phase A: attention, one token per wave per pass =================
  #pragma unroll 1
  for (int p = 0; p < TPW; ++p) {
    const int m     = tokbase + p;
    const int bidx  = m / S_;
    const int srow  = m - bidx * S_;
    const int nstar = srow & 31;

    // pv row n, features u*32..u*32+31 in registers
    const float2 pin = *(const float2*)(prec + (size_t)m * 64 + n * 2);
    float pvr[32];
    #pragma unroll
    for (int j = 0; j < 32; ++j) {
      const int e = u * 32 + j;
      pvr[j] = fmaf(pin.x, sWe0[e], fmaf(pin.y, sWe1[e], sbe[e]));
    }

    // kh, vh: fully register-local per-head DxD transforms
    float khr[32], vhr[32];
    #pragma unroll
    for (int j = 0; j < 32; ++j) { khr[j] = 0.f; vhr[j] = 0.f; }
    #pragma unroll
    for (int dp = 0; dp < 16; ++dp) {
      #pragma unroll
      for (int j = 0; j < 32; ++j) {
        const float a = pvr[(j & 16) + dp];
        khr[j] = fmaf(a, sWk[dp * 16 + (j & 15)], khr[j]);
        vhr[j] = fmaf(a, sWv[dp * 16 + (j & 15)], vhr[j]);
      }
    }

    // qh in feature layout: lane l computes qh[l]
    const int srcl = (lane & 32) + nstar;
    float qh = 0.f;
    #pragma unroll
    for (int dp = 0; dp < 16; ++dp) {
      const float a   = __shfl(pvr[dp],      srcl, 64);
      const float bsh = __shfl(pvr[16 + dp], srcl, 64);
      qh = fmaf((lane & 16) ? bsh : a, sWq[dp * 16 + (lane & 15)], qh);
    }

    // energy[h][n] for this lane's two local heads (2u, 2u+1)
    float en0 = 0.f, en1 = 0.f;
    #pragma unroll
    for (int j = 0; j < 32; ++j) {
      const float qv = __shfl(qh, (lane & 32) + j, 64);
      if (j < 16) en0 = fmaf(qv, khr[j], en0);
      else        en1 = fmaf(qv, khr[j], en1);
    }

    // mask, scale 1/sqrt(E)=1/8, softmax over n (32-lane half butterfly)
    const int tm = tmask[bidx * 32 + n];
    en0 = (tm == 0) ? -1e20f : en0;
    en1 = (tm == 0) ? -1e20f : en1;
    en0 *= 0.125f; en1 *= 0.125f;
    float mx0 = en0, mx1 = en1;
    #pragma unroll
    for (int o = 1; o < 32; o <<= 1) {
      mx0 = fmaxf(mx0, __shfl_xor(mx0, o, 64));
      mx1 = fmaxf(mx1, __shfl_xor(mx1, o, 64));
    }
    const float pe0 = __expf(en0 - mx0), pe1 = __expf(en1 - mx1);
    float s0 = pe0, s1 = pe1;
    #pragma unroll
    for (int o = 1; o < 32; o <<= 1) {
      s0 += __shfl_xor(s0, o, 64);
      s1 += __shfl_xor(s1, o, 64);
    }
    const float w0 = pe0 / s0, w1 = pe1 / s1;

    // PV: attn-weighted rows -> xor-swizzled LDS tile (conflict-free)
    const int sw = (n & 7) << 2;
    #pragma unroll
    for (int j4 = 0; j4 < 8; ++j4) {
      const float ww = (j4 < 4) ? w0 : w1;
      float4 t;
      t.x = ww * vhr[j4 * 4 + 0]; t.y = ww * vhr[j4 * 4 + 1];
      t.z = ww * vhr[j4 * 4 + 2]; t.w = ww * vhr[j4 * 4 + 3];
      *(float4*)&trans[n * 64 + ((u * 32 + j4 * 4) ^ sw)] = t;
    }
    __syncthreads();
    // column sum -> oh in feature layout
    float oh = 0.f;
    #pragma unroll
    for (int r = 0; r < 32; ++r)
      oh += trans[r * 64 + (lane ^ ((r & 7) << 2))];
    sxoh[wv][p][lane] = oh;
    __syncthreads();   // also protects trans for next pass
  }

  // ================= Phase B: ao + LN1 + FF + LN2, 8-token tile, feature layout =================
  // recompute q (residual) directly from prec (cheaper than cross-lane extraction)
  float qv[TPW];
  #pragma unroll
  for (int t = 0; t < TPW; ++t) {
    const int m     = tokbase + t;
    const int bidx  = m / S_;
    const int srow  = m - bidx * S_;
    const int nstar = srow & 31;
    const float q0 = prec[(size_t)m * 64 + nstar * 2];
    const float q1 = prec[(size_t)m * 64 + nstar * 2 + 1];
    qv[t] = fmaf(q0, sWe0[lane], fmaf(q1, sWe1[lane], sbe[lane]));
  }

  // ao = oh @ Wo + bo   (Wo streamed from global, reused across 8 tokens)
  float ao[TPW];
  #pragma unroll
  for (int t = 0; t < TPW; ++t) ao[t] = sbo[lane];
  #pragma unroll
  for (int e4 = 0; e4 < 16; ++e4) {
    const float w0_ = Wo[(e4 * 4 + 0) * 64 + lane];
    const float w1_ = Wo[(e4 * 4 + 1) * 64 + lane];
    const float w2_ = Wo[(e4 * 4 + 2) * 64 + lane];
    const float w3_ = Wo[(e4 * 4 + 3) * 64 + lane];
    #pragma unroll
    for (int t = 0; t < TPW; ++t) {
      const float4 o4 = *(const float4*)&sxoh[wv][t][e4 * 4];
      ao[t] = fmaf(o4.x, w0_, ao[t]);
      ao[t] = fmaf(o4.y, w1_, ao[t]);
      ao[t] = fmaf(o4.z, w2_, ao[t]);
      ao[t] = fmaf(o4.w, w3_, ao[t]);
    }
  }
  __syncthreads();   // before overwriting sxoh (oh) with x

  // LN1 over features (64-lane butterflies), keep x in regs + LDS for broadcast
  float xr[TPW];
  #pragma unroll
  for (int t = 0; t < TPW; ++t) {
    const float v = ao[t] + qv[t];
    float sm = v;
    #pragma unroll
    for (int o = 1; o < 64; o <<= 1) sm += __shfl_xor(sm, o, 64);
    const float mu = sm * (1.f / 64.f);
    const float d  = v - mu;
    float sq = d * d;
    #pragma unroll
    for (int o = 1; o < 64; o <<= 1) sq += __shfl_xor(sq, o, 64);
    const float rs = 1.0f / sqrtf(sq * (1.f / 64.f) + 1e-5f);
    const float x  = d * rs * sg1[lane] + sbb1[lane];
    xr[t] = x;
    sxoh[wv][t][lane] = x;
  }
  __syncthreads();

  // h1 = relu(x @ W1 + b1); lane owns columns lane+64k, k=0..3
  float hacc[TPW][4];
  #pragma unroll
  for (int t = 0; t < TPW; ++t) {
    #pragma unroll
    for (int k = 0; k < 4; ++k) hacc[t][k] = sb1[lane + 64 * k];
  }
  #pragma unroll
  for (int e4 = 0; e4 < 16; ++e4) {
    float wr[4][4];
    #pragma unroll
    for (int kk = 0; kk < 4; ++kk) {
      #pragma unroll
      for (int k = 0; k < 4; ++k)
        wr[kk][k] = W1[(e4 * 4 + kk) * 256 + lane + 64 * k];
    }
    #pragma unroll
    for (int t = 0; t < TPW; ++t) {
      const float4 xv = *(const float4*)&sxoh[wv][t][e4 * 4];
      #pragma unroll
      for (int k = 0; k < 4; ++k) {
        hacc[t][k] = fmaf(xv.x, wr[0][k], hacc[t][k]);
        hacc[t][k] = fmaf(xv.y, wr[1][k], hacc[t][k]);
        hacc[t][k] = fmaf(xv.z, wr[2][k], hacc[t][k]);
        hacc[t][k] = fmaf(xv.w, wr[3][k], hacc[t][k]);
      }
    }
  }
  float* h1buf = scratch[wv];   // overlay (trans is dead)
  #pragma unroll
  for (int t = 0; t < TPW; ++t) {
    #pragma unroll
    for (int k = 0; k < 4; ++k)
      h1buf[t * 256 + lane + 64 * k] = fmaxf(hacc[t][k], 0.f);
  }
  __syncthreads();

  // ff2 = h1 @ W2 + b2; lane owns output column `lane`
  float f2[TPW];
  #pragma unroll
  for (int t = 0; t < TPW; ++t) f2[t] = sb2c[lane];
  #pragma unroll
  for (int f4 = 0; f4 < 64; ++f4) {
    const float w0_ = W2[(f4 * 4 + 0) * 64 + lane];
    const float w1_ = W2[(f4 * 4 + 1) * 64 + lane];
    const float w2_ = W2[(f4 * 4 + 2) * 64 + lane];
    const float w3_ = W2[(f4 * 4 + 3) * 64 + lane];
    #pragma unroll
    for (int t = 0; t < TPW; ++t) {
      const float4 h4 = *(const float4*)&h1buf[t * 256 + f4 * 4];
      f2[t] = fmaf(h4.x, w0_, f2[t]);
      f2[t] = fmaf(h4.y, w1_, f2[t]);
      f2[t] = fmaf(h4.z, w2_, f2[t]);
      f2[t] = fmaf(h4.w, w3_, f2[t]);
    }
  }

  // LN2 + store
  #pragma unroll
  for (int t = 0; t < TPW; ++t) {
    const float v = f2[t] + xr[t];
    float sm = v;
    #pragma unroll
    for (int o = 1; o < 64; o <<= 1) sm += __shfl_xor(sm, o, 64);
    const float mu = sm * (1.f / 64.f);
    const float d  = v - mu;
    float sq = d * d;
    #pragma unroll
    for (int o = 1; o < 64; o <<= 1) sq += __shfl_xor(sq, o, 64);
    const float rs = 1.0f / sqrtf(sq * (1.f / 64.f) + 1e-5f);
    out[(size_t)(tokbase + t) * 64 + lane] = d * rs * sg2[lane] + sbb2[lane];
  }
}

} // namespace

extern "C" void kernel_launch(void* const* d_in, const int* in_sizes, int n_in,
                              void* d_out, int out_size, void* d_ws, size_t ws_size,
                              hipStream_t stream) {
  (void)in_sizes; (void)n_in; (void)d_ws; (void)ws_size; (void)out_size;
  const float* prec = (const float*)d_in[0];
  const int*   tm   = (const int*)  d_in[1];
  const float* We   = (const float*)d_in[2];
  const float* be   = (const float*)d_in[3];
  const float* Wq   = (const float*)d_in[4];
  const float* Wk   = (const float*)d_in[5];
  const float* Wv   = (const float*)d_in[6];
  const float* Wo   = (const float*)d_in[7];
  const float* bo   = (const float*)d_in[8];
  const float* g1   = (const float*)d_in[9];
  const float* bb1  = (const float*)d_in[10];
  const float* W1   = (const float*)d_in[11];
  const float* b1   = (const float*)d_in[12];
  const float* W2   = (const float*)d_in[13];
  const float* b2   = (const float*)d_in[14];
  const float* g2   = (const float*)d_in[15];
  const float* bb2  = (const float*)d_in[16];

  dim3 grid(768), block(256);
  hipLaunchKernelGGL(prec_fused, grid, block, 0, stream,
                     prec, tm, We, be, Wq, Wk, Wv, Wo, bo, g1, bb1,
                     W1, b1, W2, b2, g2, bb2, (float*)d_out);
}